// Round 21
// baseline (646.349 us; speedup 1.0000x reference)
//
#include <hip/hip_runtime.h>
#include <hip/hip_bf16.h>

#define U_CNT 100000
#define I_CNT 50000
#define N_CNT 150000
#define NNZ_CNT 6000000
#define CHUNK 8192
#define NSRC 733                  // ceil(6M/8192) source blocks
#define NGRP 147                  // groups of 1024 rows (row>>10)
#define GMN (NGRP * NSRC)         // 107751
#define COL_MASK 0x3FFFF

typedef unsigned short ushort_t;

__device__ __forceinline__ ushort_t f2bf_rne(float f) {
    unsigned u = __float_as_uint(f);
    unsigned r = (u + 0x7FFFu + ((u >> 16) & 1u)) >> 16;
    return (ushort_t)r;
}
__device__ __forceinline__ float bf2f(ushort_t h) {
    return __uint_as_float((unsigned)h << 16);
}

// ---------------------------------------------------------------------------
// ghist: per-source-block histogram over 147 group keys (row>>10).
// gmat[g*NSRC + b] = count of block b's edges in group g.
// ---------------------------------------------------------------------------
__global__ __launch_bounds__(1024) void ghist_kernel(
    const int* __restrict__ erow, int* __restrict__ gmat)
{
    __shared__ int h[NGRP];
    int t = threadIdx.x;
    int b = blockIdx.x;
    if (t < NGRP) h[t] = 0;
    __syncthreads();
    int base = b * CHUNK;
#pragma unroll
    for (int k = 0; k < 8; ++k) {
        int e = base + k * 1024 + t;
        if (e < NNZ_CNT) atomicAdd(&h[erow[e] >> 10], 1);
    }
    __syncthreads();
    if (t < NGRP) gmat[t * NSRC + b] = h[t];
}

// ---------------------------------------------------------------------------
// Generic 2-level exclusive scan helpers.
// ---------------------------------------------------------------------------
__global__ void scan_block_kernel(const int* __restrict__ in, int* __restrict__ out,
                                  int* __restrict__ bsum, int n) {
    __shared__ int sm[1024];
    int t = threadIdx.x;
    int i = blockIdx.x * 1024 + t;
    int v = (i < n) ? in[i] : 0;
    sm[t] = v;
    __syncthreads();
    for (int off = 1; off < 1024; off <<= 1) {
        int u = (t >= off) ? sm[t - off] : 0;
        __syncthreads();
        sm[t] += u;
        __syncthreads();
    }
    if (i < n) out[i] = sm[t] - v;
    if (t == 1023) bsum[blockIdx.x] = sm[1023];
}

__global__ void scan_small_kernel(int* __restrict__ bsum, int nb) {
    __shared__ int sm[1024];
    int t = threadIdx.x;
    int v = (t < nb) ? bsum[t] : 0;
    sm[t] = v;
    __syncthreads();
    for (int off = 1; off < 1024; off <<= 1) {
        int u = (t >= off) ? sm[t - off] : 0;
        __syncthreads();
        sm[t] += u;
        __syncthreads();
    }
    if (t < nb) bsum[t] = sm[t] - v;
}

__global__ void scan_fix_kernel(int* __restrict__ out, const int* __restrict__ boff,
                                int n, int sent_idx, int sent_val) {
    int i = blockIdx.x * 1024 + threadIdx.x;
    if (i < n) out[i] += boff[blockIdx.x];
    if (i == 0 && sent_idx >= 0) out[sent_idx] = sent_val;
}

// ---------------------------------------------------------------------------
// gplace: re-read edges; LDS cursors (147 ints) from gstart column b; write
// pre-packed records into GROUP-CONTIGUOUS regions. Active write front per
// block = 147 line-tails (~9KB) -> write-amplification ~1x.
//   pairarr[p] = (col<<14)|val14 ; rowarr[p] = row & 1023
// ---------------------------------------------------------------------------
__global__ __launch_bounds__(1024) void gplace_kernel(
    const int* __restrict__ erow, const int* __restrict__ ecol,
    const float* __restrict__ evalv, const int* __restrict__ gstart,
    unsigned* __restrict__ pairarr, ushort_t* __restrict__ rowarr)
{
    __shared__ int cur[NGRP];
    int t = threadIdx.x;
    int b = blockIdx.x;
    if (t < NGRP) cur[t] = gstart[t * NSRC + b];
    __syncthreads();
    int base = b * CHUNK;
#pragma unroll
    for (int k = 0; k < 8; ++k) {
        int e = base + k * 1024 + t;
        if (e < NNZ_CNT) {
            int r = erow[e];
            unsigned c = (unsigned)ecol[e];
            float v = evalv[e];
            unsigned v14 = (unsigned)(v * 655360.0f + 0.5f);
            if (v14 > 16383u) v14 = 16383u;
            int p = atomicAdd(&cur[r >> 10], 1);
            pairarr[p] = (c << 14) | v14;
            rowarr[p]  = (ushort_t)(r & 1023);
        }
    }
}

// ---------------------------------------------------------------------------
// rhist2: block = (group, half). Stream own half of the group's contiguous
// record region; LDS row histogram; write cnt2[row*2 + half].
// ---------------------------------------------------------------------------
__global__ __launch_bounds__(1024) void rhist2_kernel(
    const ushort_t* __restrict__ rowarr, const int* __restrict__ gstart,
    int* __restrict__ cnt2)
{
    __shared__ int cnt[1024];
    int t = threadIdx.x;
    int g = blockIdx.x >> 1;
    int h = blockIdx.x & 1;
    int s0 = gstart[g * NSRC];
    int e0 = (g == NGRP - 1) ? NNZ_CNT : gstart[(g + 1) * NSRC];
    int mid = (s0 + e0) >> 1;
    int s = h ? mid : s0;
    int e = h ? e0 : mid;
    cnt[t] = 0;
    __syncthreads();
    for (int i = s + t; i < e; i += 1024) atomicAdd(&cnt[rowarr[i]], 1);
    __syncthreads();
    int row = g * 1024 + t;
    if (row < N_CNT) cnt2[row * 2 + h] = cnt[t];
}

// ---------------------------------------------------------------------------
// place2: block = (group, half). Cursors = rp2[row*2+half]; stream own half,
// scatter pre-packed pairs into final CSR (row-contiguous; half-0 then half-1).
// ---------------------------------------------------------------------------
__global__ __launch_bounds__(1024) void place2_kernel(
    const unsigned* __restrict__ pairarr, const ushort_t* __restrict__ rowarr,
    const int* __restrict__ gstart, const int* __restrict__ rp2,
    unsigned* __restrict__ pairs4)
{
    __shared__ int cur[1024];
    int t = threadIdx.x;
    int g = blockIdx.x >> 1;
    int h = blockIdx.x & 1;
    int s0 = gstart[g * NSRC];
    int e0 = (g == NGRP - 1) ? NNZ_CNT : gstart[(g + 1) * NSRC];
    int mid = (s0 + e0) >> 1;
    int s = h ? mid : s0;
    int e = h ? e0 : mid;
    int row = g * 1024 + t;
    cur[t] = (row < N_CNT) ? rp2[row * 2 + h] : 0;
    __syncthreads();
    for (int i = s + t; i < e; i += 1024) {
        int p = atomicAdd(&cur[rowarr[i]], 1);
        pairs4[p] = pairarr[i];
    }
}

// ---------------------------------------------------------------------------
// cvt_concat: x0 = bf16(concat(user_emb, item_emb)). 8 elems/thread.
// ---------------------------------------------------------------------------
__global__ __launch_bounds__(256) void cvt_concat_kernel(
    const float* __restrict__ ue, const float* __restrict__ ie,
    ushort_t* __restrict__ x0)
{
    const size_t UE = (size_t)U_CNT * 64;
    size_t i = ((size_t)blockIdx.x * 256 + threadIdx.x) * 8;
    if (i >= (size_t)N_CNT * 64) return;
    const float* src = (i < UE) ? (ue + i) : (ie + (i - UE));
    float4 a = *(const float4*)src;
    float4 b = *(const float4*)(src + 4);
    ushort_t o[8];
    o[0] = f2bf_rne(a.x); o[1] = f2bf_rne(a.y); o[2] = f2bf_rne(a.z); o[3] = f2bf_rne(a.w);
    o[4] = f2bf_rne(b.x); o[5] = f2bf_rne(b.y); o[6] = f2bf_rne(b.z); o[7] = f2bf_rne(b.w);
    *(uint4*)(x0 + i) = *(uint4*)o;
}

// ---------------------------------------------------------------------------
// SpMM (R17-proven): wave per row, scalarized uniform pairs stream, bf16
// gather, fp32 math. Row bounds from rp2 at stride 2 (s=rp2[2r], e=rp2[2r+2]).
// ---------------------------------------------------------------------------
__global__ __launch_bounds__(256) void spmm_kernel(
    const int* __restrict__ rp2, const unsigned* __restrict__ pairs4,
    const ushort_t* __restrict__ x, ushort_t* __restrict__ y)
{
    int wave = threadIdx.x >> 6;
    int lane = threadIdx.x & 63;
    int row = blockIdx.x * 4 + wave;
    if (row >= N_CNT) return;
    int s = __builtin_amdgcn_readfirstlane(rp2[2 * row]);
    int e = __builtin_amdgcn_readfirstlane(rp2[2 * row + 2]);
    const char* xb = (const char*)x;
    unsigned lane2 = (unsigned)(lane << 1);
    const float VQ = 1.52587890625e-06f;   // 1/655360
    float sum = 0.f;
    int i = s;
    for (; i + 7 < e; i += 8) {
        unsigned p[8];
#pragma unroll
        for (int k = 0; k < 8; ++k) p[k] = pairs4[i + k];
        ushort_t a[8];
#pragma unroll
        for (int k = 0; k < 8; ++k)
            a[k] = *(const ushort_t*)(xb + (((p[k] & 0xFFFFC000u) >> 7) | lane2));
#pragma unroll
        for (int k = 0; k < 8; ++k)
            sum = fmaf((float)(p[k] & 16383u) * VQ, bf2f(a[k]), sum);
    }
    for (; i < e; ++i) {
        unsigned p = pairs4[i];
        ushort_t av = *(const ushort_t*)(xb + (((p & 0xFFFFC000u) >> 7) | lane2));
        sum = fmaf((float)(p & 16383u) * VQ, bf2f(av), sum);
    }
    y[(size_t)row * 64 + lane] = f2bf_rne(sum);
}

// ---------------------------------------------------------------------------
// Fused dual 2-layer MLP (unchanged). Input row = (x1+x2+x3)/3 on the fly.
// ---------------------------------------------------------------------------
#define WST 68
__global__ __launch_bounds__(256) void mlp_dual_kernel(
    const ushort_t* __restrict__ x1p, const ushort_t* __restrict__ x2p,
    const ushort_t* __restrict__ x3p, int row_s, int row_e, float scale,
    const float* __restrict__ Ws1, const float* __restrict__ bs1,
    const float* __restrict__ Ws2, const float* __restrict__ bs2,
    const float* __restrict__ Wx1, const float* __restrict__ bx1,
    const float* __restrict__ Wx2, const float* __restrict__ bx2,
    float* __restrict__ out_s, float* __restrict__ out_x)
{
    __shared__ float S1[64 * WST], S2[64 * WST], X1[64 * WST], X2[64 * WST];
    __shared__ float rbuf[4][64], h1buf[4][64], h2buf[4][64];

    int t = threadIdx.x;
    for (int idx = t; idx < 4096; idx += 256) {
        int d = idx >> 6, k = idx & 63;
        S1[d * WST + k] = Ws1[idx];
        S2[d * WST + k] = Ws2[idx];
        X1[d * WST + k] = Wx1[idx];
        X2[d * WST + k] = Wx2[idx];
    }
    __syncthreads();

    int wave = t >> 6, lane = t & 63;
    float vbs1 = bs1[lane], vbs2 = bs2[lane];
    float vbx1 = bx1[lane], vbx2 = bx2[lane];
    const float4* s1v = (const float4*)&S1[lane * WST];
    const float4* s2v = (const float4*)&S2[lane * WST];
    const float4* x1v = (const float4*)&X1[lane * WST];
    const float4* x2v = (const float4*)&X2[lane * WST];

    for (int r = row_s + blockIdx.x * 4 + wave; r < row_e; r += gridDim.x * 4) {
        size_t o = (size_t)r * 64 + lane;
        float xv = (bf2f(x1p[o]) + bf2f(x2p[o]) + bf2f(x3p[o])) * scale;
        rbuf[wave][lane] = xv;
        float h1 = vbs1, h2 = vbx1;
#pragma unroll
        for (int k4 = 0; k4 < 16; ++k4) {
            float4 rv = *(const float4*)&rbuf[wave][k4 * 4];
            float4 w1 = s1v[k4];
            float4 w2 = x1v[k4];
            h1 = fmaf(rv.x, w1.x, h1); h1 = fmaf(rv.y, w1.y, h1);
            h1 = fmaf(rv.z, w1.z, h1); h1 = fmaf(rv.w, w1.w, h1);
            h2 = fmaf(rv.x, w2.x, h2); h2 = fmaf(rv.y, w2.y, h2);
            h2 = fmaf(rv.z, w2.z, h2); h2 = fmaf(rv.w, w2.w, h2);
        }
        h1 = fmaxf(h1, 0.f);
        h2 = fmaxf(h2, 0.f);
        h1buf[wave][lane] = h1;
        h2buf[wave][lane] = h2;
        float y1 = vbs2, y2 = vbx2;
#pragma unroll
        for (int k4 = 0; k4 < 16; ++k4) {
            float4 a1 = *(const float4*)&h1buf[wave][k4 * 4];
            float4 a2 = *(const float4*)&h2buf[wave][k4 * 4];
            float4 w1 = s2v[k4];
            float4 w2 = x2v[k4];
            y1 = fmaf(a1.x, w1.x, y1); y1 = fmaf(a1.y, w1.y, y1);
            y1 = fmaf(a1.z, w1.z, y1); y1 = fmaf(a1.w, w1.w, y1);
            y2 = fmaf(a2.x, w2.x, y2); y2 = fmaf(a2.y, w2.y, y2);
            y2 = fmaf(a2.z, w2.z, y2); y2 = fmaf(a2.w, w2.w, y2);
        }
        out_s[(size_t)r * 64 + lane] = y1;
        out_x[(size_t)r * 64 + lane] = y2;
    }
}

// ---------------------------------------------------------------------------

extern "C" void kernel_launch(void* const* d_in, const int* in_sizes, int n_in,
                              void* d_out, int out_size, void* d_ws, size_t ws_size,
                              hipStream_t stream)
{
    (void)in_sizes; (void)n_in; (void)out_size; (void)ws_size;

    const float* user_emb = (const float*)d_in[0];
    const float* item_emb = (const float*)d_in[1];
    const int*   erow     = (const int*)d_in[2];
    const int*   ecol     = (const int*)d_in[3];
    const float* evalv    = (const float*)d_in[4];
    const float* Wsg1 = (const float*)d_in[5];
    const float* bsg1 = (const float*)d_in[6];
    const float* Wsg2 = (const float*)d_in[7];
    const float* bsg2 = (const float*)d_in[8];
    const float* Wuf1 = (const float*)d_in[9];
    const float* buf1 = (const float*)d_in[10];
    const float* Wuf2 = (const float*)d_in[11];
    const float* buf2 = (const float*)d_in[12];
    const float* Wif1 = (const float*)d_in[13];
    const float* bif1 = (const float*)d_in[14];
    const float* Wif2 = (const float*)d_in[15];
    const float* bif2 = (const float*)d_in[16];

    float* out = (float*)d_out;
    const size_t XB = (size_t)N_CNT * 64;   // 9.6M elements per node-buffer

    // d_out layout (76.8 MB):
    //   pairarr 24MB @ [0, 6M floats) | rowarr 12MB @ [6M, 9M) |
    //   x0 19.2MB @ [9M, 13.8M)
    // pairarr/rowarr dead after place2; x0 dead after spmm layer 1;
    // MLPs overwrite out[0, 19.2M floats) at the end.
    unsigned* pairarr = (unsigned*)out;
    ushort_t* rowarr  = (ushort_t*)(out + 6000000);
    ushort_t* x0      = (ushort_t*)(out + 9000000);

    // workspace (~85 MB):
    char* ws = (char*)d_ws;
    ushort_t* x1     = (ushort_t*)ws;                                 // 19.2 MB
    ushort_t* x2     = x1 + XB;                                       // 19.2 MB
    ushort_t* x3     = x2 + XB;                                       // 19.2 MB
    unsigned* pairs4 = (unsigned*)(ws + XB * 6);                      // 24 MB
    int*      rp2    = (int*)(ws + XB * 6 + (size_t)NNZ_CNT * 4);     // 300001+pad
    int*      cnt2   = rp2 + 300008;                                  // 300000
    int*      gmat   = cnt2 + 300000;                                 // GMN
    int*      gstart = gmat + GMN + 8;                                // GMN+1 (+pad)
    int*      bsumA  = gstart + GMN + 8;                              // 128
    int*      bsumD  = bsumA + 128;                                   // 320

    const int NBA = (GMN + 1023) / 1024;        // 106
    const int NBD = (300000 + 1023) / 1024;     // 293

    // ---- build: group hist -> scan -> group-contiguous place ----
    ghist_kernel<<<NSRC, 1024, 0, stream>>>(erow, gmat);
    scan_block_kernel<<<NBA, 1024, 0, stream>>>(gmat, gstart, bsumA, GMN);
    scan_small_kernel<<<1, 1024, 0, stream>>>(bsumA, NBA);
    scan_fix_kernel<<<NBA, 1024, 0, stream>>>(gstart, bsumA, GMN, GMN, NNZ_CNT);
    gplace_kernel<<<NSRC, 1024, 0, stream>>>(erow, ecol, evalv, gstart, pairarr, rowarr);

    // ---- per-(row,half) counts -> scan -> final CSR placement ----
    rhist2_kernel<<<NGRP * 2, 1024, 0, stream>>>(rowarr, gstart, cnt2);
    scan_block_kernel<<<NBD, 1024, 0, stream>>>(cnt2, rp2, bsumD, 300000);
    scan_small_kernel<<<1, 1024, 0, stream>>>(bsumD, NBD);
    scan_fix_kernel<<<NBD, 1024, 0, stream>>>(rp2, bsumD, 300000, 300000, NNZ_CNT);
    place2_kernel<<<NGRP * 2, 1024, 0, stream>>>(pairarr, rowarr, gstart, rp2, pairs4);

    // ---- x0 = bf16(concat(user_emb, item_emb)) ----
    cvt_concat_kernel<<<(int)((XB / 8 + 255) / 256), 256, 0, stream>>>(user_emb, item_emb, x0);

    // ---- 3 propagation layers (bf16 gather; outputs kept, no acc) ----
    int sg = N_CNT / 4;  // 37500
    spmm_kernel<<<sg, 256, 0, stream>>>(rp2, pairs4, x0, x1);
    spmm_kernel<<<sg, 256, 0, stream>>>(rp2, pairs4, x1, x2);
    spmm_kernel<<<sg, 256, 0, stream>>>(rp2, pairs4, x2, x3);

    // ---- fused MLP heads (shared + user / shared + item), overwrite d_out ----
    const float sc = 1.0f / 3.0f;
    mlp_dual_kernel<<<512, 256, 0, stream>>>(x1, x2, x3, 0, U_CNT, sc,
        Wsg1, bsg1, Wsg2, bsg2, Wuf1, buf1, Wuf2, buf2, out, out + XB);
    mlp_dual_kernel<<<512, 256, 0, stream>>>(x1, x2, x3, U_CNT, N_CNT, sc,
        Wsg1, bsg1, Wsg2, bsg2, Wif1, bif1, Wif2, bif2, out, out + XB);
}

// Round 22
// 604.094 us; speedup vs baseline: 1.0699x; 1.0699x over previous
//
#include <hip/hip_runtime.h>
#include <hip/hip_bf16.h>

#define U_CNT 100000
#define I_CNT 50000
#define N_CNT 150000
#define NNZ_CNT 6000000
#define NBKT 1172                 // ceil(150000/128) buckets of 128 rows
#define OFFW (NBKT + 1)           // 1173
#define CHUNK 8192
#define NBLK_BIN 733              // ceil(6M/8192)
#define NGRP 293                  // groups of 512 rows (4 buckets each; 1172/4)
#define COL_MASK 0x3FFFF          // 18 bits (N=150000 < 2^18)

typedef unsigned short ushort_t;

__device__ __forceinline__ ushort_t f2bf_rne(float f) {
    unsigned u = __float_as_uint(f);
    unsigned r = (u + 0x7FFFu + ((u >> 16) & 1u)) >> 16;
    return (ushort_t)r;
}
__device__ __forceinline__ float bf2f(ushort_t h) {
    return __uint_as_float((unsigned)h << 16);
}

// ---------------------------------------------------------------------------
// bin_sort: per-block LDS counting sort by bucket (row>>7), CHUNK=8192,
// ONE PASS (edges staged in registers). Emits PRE-PACKED split arrays:
//   pairarr[i] = (col<<14)|val14   (final spmm pair format, 4B)
//   rowarr[i]  = row & 511         (group-local row for 512-row groups, 2B)
// block-major, write-once. offM[g][b] = segment starts; gcnt = group counts.
// ---------------------------------------------------------------------------
__global__ __launch_bounds__(1024) void bin_sort_kernel(
    const int* __restrict__ erow, const int* __restrict__ ecol,
    const float* __restrict__ evalv,
    unsigned* __restrict__ pairarr, ushort_t* __restrict__ rowarr,
    int* __restrict__ offM, int* __restrict__ gcnt)
{
    __shared__ unsigned stage_pair[CHUNK];   // 32 KB; low 8 KB = scan temp
    __shared__ ushort_t stage_row[CHUNK];    // 16 KB
    __shared__ int      hist[NBKT];
    __shared__ int      lbase[NBKT];

    int t = threadIdx.x;
    int g = blockIdx.x;
    int base = g * CHUNK;
    int n = NNZ_CNT - base; if (n > CHUNK) n = CHUNK;

    // load once into registers
    int rows[8]; unsigned pk[8];
#pragma unroll
    for (int k = 0; k < 8; ++k) {
        int e = base + k * 1024 + t;
        bool ok = (e < NNZ_CNT);
        rows[k] = ok ? erow[e] : -1;
        unsigned c = ok ? (unsigned)ecol[e] : 0u;
        float v = ok ? evalv[e] : 0.f;
        unsigned v14 = (unsigned)(v * 655360.0f + 0.5f);
        if (v14 > 16383u) v14 = 16383u;
        pk[k] = (c << 14) | v14;
    }

    for (int i = t; i < NBKT; i += 1024) hist[i] = 0;
    __syncthreads();

    // bucket histogram
#pragma unroll
    for (int k = 0; k < 8; ++k)
        if (rows[k] >= 0) atomicAdd(&hist[rows[k] >> 7], 1);
    __syncthreads();

    // per-group global counts (4 buckets per 512-row group)
    for (int i = t; i < NGRP; i += 1024) {
        int s = 0;
#pragma unroll
        for (int j = 0; j < 4; ++j) {
            int b = i * 4 + j;
            if (b < NBKT) s += hist[b];
        }
        if (s) atomicAdd(&gcnt[i], s);
    }

    // exclusive scan of hist (2048-wide two-half Hillis in stage temp)
    int* sc = (int*)stage_pair;
    int v0 = (t < NBKT) ? hist[t] : 0;
    int v1 = (1024 + t < NBKT) ? hist[1024 + t] : 0;
    sc[t] = v0; sc[1024 + t] = v1;
    __syncthreads();
    for (int off = 1; off < 1024; off <<= 1) {
        int u0 = (t >= off) ? sc[t - off] : 0;
        int u1 = (t >= off) ? sc[1024 + t - off] : 0;
        __syncthreads();
        sc[t] += u0; sc[1024 + t] += u1;
        __syncthreads();
    }
    int tot0 = sc[1023];
    if (t < NBKT) lbase[t] = sc[t] - v0;
    if (1024 + t < NBKT) lbase[1024 + t] = tot0 + sc[1024 + t] - v1;
    __syncthreads();

    // reset hist as scatter cursors
    for (int i = t; i < NBKT; i += 1024) hist[i] = 0;
    __syncthreads();

    // scatter from registers into LDS stage (bucket-major in block)
#pragma unroll
    for (int k = 0; k < 8; ++k) {
        if (rows[k] >= 0) {
            int b = rows[k] >> 7;
            int p = lbase[b] + atomicAdd(&hist[b], 1);
            stage_pair[p] = pk[k];
            stage_row[p]  = (ushort_t)(rows[k] & 511);
        }
    }
    __syncthreads();

    // stream out block's private regions (coalesced, full lines, write-once)
    for (int i = t; i < n; i += 1024) pairarr[base + i] = stage_pair[i];
    for (int i = t; i < n; i += 1024) rowarr[base + i]  = stage_row[i];

    // per-block bucket offsets
    for (int i = t; i < NBKT; i += 1024)
        offM[(size_t)g * OFFW + i] = base + lbase[i];
    if (t == 0) offM[(size_t)g * OFFW + NBKT] = base + n;
}

// ---------------------------------------------------------------------------
// gscan: exclusive scan of gcnt[293] -> gbase; writes rp[N] sentinel.
// ---------------------------------------------------------------------------
__global__ __launch_bounds__(512) void gscan_kernel(
    const int* __restrict__ gcnt, int* __restrict__ gbase, int* __restrict__ rp)
{
    __shared__ int sm[512];
    int t = threadIdx.x;
    int v = (t < NGRP) ? gcnt[t] : 0;
    sm[t] = v;
    __syncthreads();
    for (int off = 1; off < 512; off <<= 1) {
        int u = (t >= off) ? sm[t - off] : 0;
        __syncthreads();
        sm[t] += u;
        __syncthreads();
    }
    if (t < NGRP) gbase[t] = sm[t] - v;
    if (t == 0) rp[N_CNT] = NNZ_CNT;
}

// ---------------------------------------------------------------------------
// build_csr: block = group of 4 buckets (512 rows) -> 293 blocks (2x the old
// occupancy; R18 showed 23% occupancy / half the GPU idle was the limiter).
// Per source block g the group's records are CONTIGUOUS:
// [offM[g][b0], offM[g][b0+4]) — avg ~28 records.
// Phase 1: LDS row histogram from rowarr. Phase 2: LDS scan + gbase -> rp +
// cursors. Phase 3: gather rowarr+pairarr, scatter pairarr verbatim.
// ---------------------------------------------------------------------------
__global__ __launch_bounds__(1024) void build_csr_kernel(
    const unsigned* __restrict__ pairarr, const ushort_t* __restrict__ rowarr,
    const int* __restrict__ offM, const int* __restrict__ gbase,
    int* __restrict__ rp, unsigned* __restrict__ pairs4)
{
    __shared__ int lcnt[512];
    __shared__ int cur[512];
    int t = threadIdx.x;
    int blk = blockIdx.x;
    int b0 = blk * 4;
    int bend = b0 + 4; if (bend > NBKT) bend = NBKT;

    if (t < 512) lcnt[t] = 0;
    __syncthreads();

    int wid = t >> 6, lane = t & 63;

    // phase 1: row histogram (2-byte reads)
    for (int g = wid; g < NBLK_BIN; g += 16) {
        size_t o = (size_t)g * OFFW;
        int s = offM[o + b0], e = offM[o + bend];
        for (int i = s + lane; i < e; i += 64)
            atomicAdd(&lcnt[rowarr[i]], 1);
    }
    __syncthreads();

    // phase 2: exclusive scan (512 participants) + global base -> cursors, rp
    int v = (t < 512) ? lcnt[t] : 0;
    __syncthreads();
    for (int off = 1; off < 512; off <<= 1) {
        int u = (t >= off && t < 512) ? lcnt[t - off] : 0;
        __syncthreads();
        if (t < 512) lcnt[t] += u;
        __syncthreads();
    }
    if (t < 512) {
        int abs0 = gbase[blk] + lcnt[t] - v;   // exclusive + base
        cur[t] = abs0;
        int row = blk * 512 + t;
        if (row < N_CNT) rp[row] = abs0;
    }
    __syncthreads();

    // phase 3: place pre-packed records
    for (int g = wid; g < NBLK_BIN; g += 16) {
        size_t o = (size_t)g * OFFW;
        int s = offM[o + b0], e = offM[o + bend];
        for (int i = s + lane; i < e; i += 64) {
            int p = atomicAdd(&cur[rowarr[i]], 1);
            pairs4[p] = pairarr[i];
        }
    }
}

// ---------------------------------------------------------------------------
// cvt_concat: x0 = bf16(concat(user_emb, item_emb)). 8 elems/thread.
// ---------------------------------------------------------------------------
__global__ __launch_bounds__(256) void cvt_concat_kernel(
    const float* __restrict__ ue, const float* __restrict__ ie,
    ushort_t* __restrict__ x0)
{
    const size_t UE = (size_t)U_CNT * 64;   // 6.4M (divisible by 8)
    size_t i = ((size_t)blockIdx.x * 256 + threadIdx.x) * 8;
    if (i >= (size_t)N_CNT * 64) return;
    const float* src = (i < UE) ? (ue + i) : (ie + (i - UE));
    float4 a = *(const float4*)src;
    float4 b = *(const float4*)(src + 4);
    ushort_t o[8];
    o[0] = f2bf_rne(a.x); o[1] = f2bf_rne(a.y); o[2] = f2bf_rne(a.z); o[3] = f2bf_rne(a.w);
    o[4] = f2bf_rne(b.x); o[5] = f2bf_rne(b.y); o[6] = f2bf_rne(b.z); o[7] = f2bf_rne(b.w);
    *(uint4*)(x0 + i) = *(uint4*)o;
}

// ---------------------------------------------------------------------------
// SpMM (R17-proven, 107.7 us/layer): wave per row, scalarized uniform pairs
// stream (readfirstlane -> s_load), bf16 gather, fp32 math.
// ---------------------------------------------------------------------------
__global__ __launch_bounds__(256) void spmm_kernel(
    const int* __restrict__ rp, const unsigned* __restrict__ pairs4,
    const ushort_t* __restrict__ x, ushort_t* __restrict__ y)
{
    int wave = threadIdx.x >> 6;
    int lane = threadIdx.x & 63;
    int row = blockIdx.x * 4 + wave;
    if (row >= N_CNT) return;
    int s = __builtin_amdgcn_readfirstlane(rp[row]);
    int e = __builtin_amdgcn_readfirstlane(rp[row + 1]);
    const char* xb = (const char*)x;
    unsigned lane2 = (unsigned)(lane << 1);
    const float VQ = 1.52587890625e-06f;   // 1/655360
    float sum = 0.f;
    int i = s;
    for (; i + 7 < e; i += 8) {
        unsigned p[8];
#pragma unroll
        for (int k = 0; k < 8; ++k) p[k] = pairs4[i + k];
        ushort_t a[8];
#pragma unroll
        for (int k = 0; k < 8; ++k)
            a[k] = *(const ushort_t*)(xb + (((p[k] & 0xFFFFC000u) >> 7) | lane2));
#pragma unroll
        for (int k = 0; k < 8; ++k)
            sum = fmaf((float)(p[k] & 16383u) * VQ, bf2f(a[k]), sum);
    }
    for (; i < e; ++i) {
        unsigned p = pairs4[i];
        ushort_t av = *(const ushort_t*)(xb + (((p & 0xFFFFC000u) >> 7) | lane2));
        sum = fmaf((float)(p & 16383u) * VQ, bf2f(av), sum);
    }
    y[(size_t)row * 64 + lane] = f2bf_rne(sum);
}

// ---------------------------------------------------------------------------
// Fused dual 2-layer MLP (unchanged). Input row = (x1+x2+x3)/3 on the fly.
// ---------------------------------------------------------------------------
#define WST 68
__global__ __launch_bounds__(256) void mlp_dual_kernel(
    const ushort_t* __restrict__ x1p, const ushort_t* __restrict__ x2p,
    const ushort_t* __restrict__ x3p, int row_s, int row_e, float scale,
    const float* __restrict__ Ws1, const float* __restrict__ bs1,
    const float* __restrict__ Ws2, const float* __restrict__ bs2,
    const float* __restrict__ Wx1, const float* __restrict__ bx1,
    const float* __restrict__ Wx2, const float* __restrict__ bx2,
    float* __restrict__ out_s, float* __restrict__ out_x)
{
    __shared__ float S1[64 * WST], S2[64 * WST], X1[64 * WST], X2[64 * WST];
    __shared__ float rbuf[4][64], h1buf[4][64], h2buf[4][64];

    int t = threadIdx.x;
    for (int idx = t; idx < 4096; idx += 256) {
        int d = idx >> 6, k = idx & 63;
        S1[d * WST + k] = Ws1[idx];
        S2[d * WST + k] = Ws2[idx];
        X1[d * WST + k] = Wx1[idx];
        X2[d * WST + k] = Wx2[idx];
    }
    __syncthreads();

    int wave = t >> 6, lane = t & 63;
    float vbs1 = bs1[lane], vbs2 = bs2[lane];
    float vbx1 = bx1[lane], vbx2 = bx2[lane];
    const float4* s1v = (const float4*)&S1[lane * WST];
    const float4* s2v = (const float4*)&S2[lane * WST];
    const float4* x1v = (const float4*)&X1[lane * WST];
    const float4* x2v = (const float4*)&X2[lane * WST];

    for (int r = row_s + blockIdx.x * 4 + wave; r < row_e; r += gridDim.x * 4) {
        size_t o = (size_t)r * 64 + lane;
        float xv = (bf2f(x1p[o]) + bf2f(x2p[o]) + bf2f(x3p[o])) * scale;
        rbuf[wave][lane] = xv;           // same-wave produce/consume
        float h1 = vbs1, h2 = vbx1;
#pragma unroll
        for (int k4 = 0; k4 < 16; ++k4) {
            float4 rv = *(const float4*)&rbuf[wave][k4 * 4];
            float4 w1 = s1v[k4];
            float4 w2 = x1v[k4];
            h1 = fmaf(rv.x, w1.x, h1); h1 = fmaf(rv.y, w1.y, h1);
            h1 = fmaf(rv.z, w1.z, h1); h1 = fmaf(rv.w, w1.w, h1);
            h2 = fmaf(rv.x, w2.x, h2); h2 = fmaf(rv.y, w2.y, h2);
            h2 = fmaf(rv.z, w2.z, h2); h2 = fmaf(rv.w, w2.w, h2);
        }
        h1 = fmaxf(h1, 0.f);
        h2 = fmaxf(h2, 0.f);
        h1buf[wave][lane] = h1;
        h2buf[wave][lane] = h2;
        float y1 = vbs2, y2 = vbx2;
#pragma unroll
        for (int k4 = 0; k4 < 16; ++k4) {
            float4 a1 = *(const float4*)&h1buf[wave][k4 * 4];
            float4 a2 = *(const float4*)&h2buf[wave][k4 * 4];
            float4 w1 = s2v[k4];
            float4 w2 = x2v[k4];
            y1 = fmaf(a1.x, w1.x, y1); y1 = fmaf(a1.y, w1.y, y1);
            y1 = fmaf(a1.z, w1.z, y1); y1 = fmaf(a1.w, w1.w, y1);
            y2 = fmaf(a2.x, w2.x, y2); y2 = fmaf(a2.y, w2.y, y2);
            y2 = fmaf(a2.z, w2.z, y2); y2 = fmaf(a2.w, w2.w, y2);
        }
        out_s[(size_t)r * 64 + lane] = y1;
        out_x[(size_t)r * 64 + lane] = y2;
    }
}

// ---------------------------------------------------------------------------

extern "C" void kernel_launch(void* const* d_in, const int* in_sizes, int n_in,
                              void* d_out, int out_size, void* d_ws, size_t ws_size,
                              hipStream_t stream)
{
    (void)in_sizes; (void)n_in; (void)out_size; (void)ws_size;

    const float* user_emb = (const float*)d_in[0];
    const float* item_emb = (const float*)d_in[1];
    const int*   erow     = (const int*)d_in[2];
    const int*   ecol     = (const int*)d_in[3];
    const float* evalv    = (const float*)d_in[4];
    const float* Wsg1 = (const float*)d_in[5];
    const float* bsg1 = (const float*)d_in[6];
    const float* Wsg2 = (const float*)d_in[7];
    const float* bsg2 = (const float*)d_in[8];
    const float* Wuf1 = (const float*)d_in[9];
    const float* buf1 = (const float*)d_in[10];
    const float* Wuf2 = (const float*)d_in[11];
    const float* buf2 = (const float*)d_in[12];
    const float* Wif1 = (const float*)d_in[13];
    const float* bif1 = (const float*)d_in[14];
    const float* Wif2 = (const float*)d_in[15];
    const float* bif2 = (const float*)d_in[16];

    float* out = (float*)d_out;
    const size_t XB = (size_t)N_CNT * 64;   // 9.6M elements per node-buffer

    // d_out layout (76.8 MB):
    //   pairarr 24MB @ [0, 6M floats) | rowarr 12MB @ [6M, 9M) |
    //   offM 6.9MB @ [9M, ~10.72M)    | x0 19.2MB @ [12M, 16.8M)
    // pairarr/rowarr/offM dead after build_csr; x0 dead after spmm layer 1;
    // MLPs overwrite out[0, 19.2M floats) at the end.
    unsigned* pairarr = (unsigned*)out;
    ushort_t* rowarr  = (ushort_t*)(out + 6000000);
    int*      offM    = (int*)(out + 9000000);
    ushort_t* x0      = (ushort_t*)(out + 12000000);

    // workspace (~82.2 MB): three bf16 layer outputs + packed pairs + rp
    char* ws = (char*)d_ws;
    ushort_t* x1     = (ushort_t*)ws;                                 // 19.2 MB
    ushort_t* x2     = x1 + XB;                                       // 19.2 MB
    ushort_t* x3     = x2 + XB;                                       // 19.2 MB
    unsigned* pairs4 = (unsigned*)(ws + XB * 6);                      // 24 MB
    int*      rp     = (int*)(ws + XB * 6 + (size_t)NNZ_CNT * 4);     // N+1 (+pad)
    int*      gcnt   = rp + N_CNT + 8;                                // 320
    int*      gbase  = gcnt + 320;                                    // 320

    // ---- build: bin (1-pass, pre-packed) -> group scan -> hist/scan/place ----
    hipMemsetAsync(gcnt, 0, NGRP * sizeof(int), stream);
    bin_sort_kernel<<<NBLK_BIN, 1024, 0, stream>>>(erow, ecol, evalv,
                                                   pairarr, rowarr, offM, gcnt);
    gscan_kernel<<<1, 512, 0, stream>>>(gcnt, gbase, rp);
    build_csr_kernel<<<NGRP, 1024, 0, stream>>>(pairarr, rowarr, offM, gbase,
                                                rp, pairs4);

    // ---- x0 = bf16(concat(user_emb, item_emb)) ----
    cvt_concat_kernel<<<(int)((XB / 8 + 255) / 256), 256, 0, stream>>>(user_emb, item_emb, x0);

    // ---- 3 propagation layers (bf16 gather; outputs kept, no acc) ----
    int sg = N_CNT / 4;  // 37500
    spmm_kernel<<<sg, 256, 0, stream>>>(rp, pairs4, x0, x1);
    spmm_kernel<<<sg, 256, 0, stream>>>(rp, pairs4, x1, x2);
    spmm_kernel<<<sg, 256, 0, stream>>>(rp, pairs4, x2, x3);

    // ---- fused MLP heads (shared + user / shared + item), overwrite d_out ----
    const float sc = 1.0f / 3.0f;
    mlp_dual_kernel<<<512, 256, 0, stream>>>(x1, x2, x3, 0, U_CNT, sc,
        Wsg1, bsg1, Wsg2, bsg2, Wuf1, buf1, Wuf2, buf2, out, out + XB);
    mlp_dual_kernel<<<512, 256, 0, stream>>>(x1, x2, x3, U_CNT, N_CNT, sc,
        Wsg1, bsg1, Wsg2, bsg2, Wif1, bif1, Wif2, bif2, out, out + XB);
}